// Round 7
// baseline (137.864 us; speedup 1.0000x reference)
//
#include <hip/hip_runtime.h>
#include <stdint.h>

// FP4 quant-dequant, faithful to the JAX reference in float32 arithmetic.
// v9 = v2 byte-identical EXCEPT k_scales load layout (one-change discipline;
// v8 bundled this with WGS=1024 which cost ~9us and masked it).
// Overhead model (fit over v2/v5/v7/v8): dur ~= 87us fixed harness cost
// (2x41.5us 256MiB ws-poison fills + launch/sync) + sum(kernels); v2's
// kernels ~= 41us vs ~30us structural floor. k_scales is the only kernel
// plausibly above floor: fat-thread layout = 256-B lane stride = 4x line-
// transaction rate. v9: 8 lanes per 64-block, lane l loads float4 l and l+8
// -> 16 fully-utilized 64-B lines per wave instruction (ideal coalescing);
// exact top-5 via per-lane ins5 + 3-step shfl_xor merge (order-independent,
// verified bit-identical in v3/v4/v8). k_reduce/k_quant verbatim from v2.

#define BLK 64
#define WG 256
#define FLT_BIG 3.402823466e+38f

// Branchless insert of `a` into descending-sorted top-5 register array.
__device__ __forceinline__ void ins5(float (&t)[5], float a) {
#pragma unroll
    for (int k = 0; k < 4; ++k) {
        float m = fmaxf(t[k], a);
        a = fminf(t[k], a);
        t[k] = m;
    }
    t[4] = fmaxf(t[4], a);
}

// JAX f32 quantile: q = 0.95f*63.0f; result = v59*lw + v60*hw
__device__ __forceinline__ float quantile5(const float (&A)[5]) {
    const float qs = 0.95f * 63.0f;      // 59.849998474121094f
    const float hw = qs - 59.0f;
    const float lw = 60.0f - qs;
    // A[3] = 4th largest = sorted v[60]; A[4] = 5th largest = v[59]
    float s = __fadd_rn(__fmul_rn(A[4], lw), __fmul_rn(A[3], hw));
    return fmaxf(s, 1e-8f);
}

// Nearest FP4 level via boundary ladder on the EXACT quotient fl(x/s).
// Midpoints and partial sums are exact dyadics; ties at exact midpoints go
// to the lower-index (more negative) level, matching argmin-first-index.
__device__ __forceinline__ float qlevel(float xn) {
    float bv = -3.0f;
    bv += (xn > -2.5f)   ? 1.0f  : 0.0f;
    bv += (xn > -1.75f)  ? 0.5f  : 0.0f;
    bv += (xn > -1.25f)  ? 0.5f  : 0.0f;
    bv += (xn > -0.875f) ? 0.25f : 0.0f;
    bv += (xn > -0.375f) ? 0.75f : 0.0f;
    bv += (xn > 0.375f)  ? 0.75f : 0.0f;
    bv += (xn > 0.875f)  ? 0.25f : 0.0f;
    bv += (xn > 1.25f)   ? 0.5f  : 0.0f;
    bv += (xn > 1.75f)   ? 0.5f  : 0.0f;
    bv += (xn > 2.5f)    ? 1.0f  : 0.0f;
    return bv;
}

// ---------------- Kernel 1: per-block scales, coalesced, WG=256 ----------------
// 8 lanes own one 64-elem block (32 blocks per WG). Lane l loads float4 #l
// and #(l+8): per wave instruction, 16 fully-utilized 64-B lines. Per-lane
// exact top-5 of its 8 |x|, then 3-step shfl_xor merge (offsets 1,2,4 stay
// inside the aligned 8-lane group) -> all 8 lanes hold the block's exact top-5.
__global__ __launch_bounds__(WG) void k_scales(const float* __restrict__ x,
                                               int n, int nblocks,
                                               float* __restrict__ scales,
                                               float* __restrict__ partMin,
                                               float* __restrict__ partMax) {
    const int tid = (int)threadIdx.x;
    const int lanein = tid & 7;
    const int b = (int)blockIdx.x * (WG / 8) + (tid >> 3);
    const bool valid = (b < nblocks);

    float s = 0.0f;
    if (valid) {
        const int base = b * BLK;
        float4 v0, v1;
        if (base + BLK <= n) {
            const float4* x4 = reinterpret_cast<const float4*>(x + base);
            v0 = x4[lanein];
            v1 = x4[lanein + 8];
        } else {
            const int i0 = base + lanein * 4;
            const int i1 = i0 + 32;
            v0.x = (i0 + 0 < n) ? x[i0 + 0] : 0.0f;   // reference zero-pads
            v0.y = (i0 + 1 < n) ? x[i0 + 1] : 0.0f;
            v0.z = (i0 + 2 < n) ? x[i0 + 2] : 0.0f;
            v0.w = (i0 + 3 < n) ? x[i0 + 3] : 0.0f;
            v1.x = (i1 + 0 < n) ? x[i1 + 0] : 0.0f;
            v1.y = (i1 + 1 < n) ? x[i1 + 1] : 0.0f;
            v1.z = (i1 + 2 < n) ? x[i1 + 2] : 0.0f;
            v1.w = (i1 + 3 < n) ? x[i1 + 3] : 0.0f;
        }
        // Per-lane exact top-5 of its 8 |x| (abs>=0 so 0-init is safe).
        float A[5] = {0.f, 0.f, 0.f, 0.f, 0.f};
        ins5(A, fabsf(v0.x)); ins5(A, fabsf(v0.y));
        ins5(A, fabsf(v0.z)); ins5(A, fabsf(v0.w));
        ins5(A, fabsf(v1.x)); ins5(A, fabsf(v1.y));
        ins5(A, fabsf(v1.z)); ins5(A, fabsf(v1.w));
        // Merge across the 8-lane group: exact top-5 of the block's 64 elems.
#pragma unroll
        for (int m = 1; m <= 4; m <<= 1) {
            float o0 = __shfl_xor(A[0], m, 64);
            float o1 = __shfl_xor(A[1], m, 64);
            float o2 = __shfl_xor(A[2], m, 64);
            float o3 = __shfl_xor(A[3], m, 64);
            float o4 = __shfl_xor(A[4], m, 64);
            ins5(A, o0); ins5(A, o1); ins5(A, o2); ins5(A, o3); ins5(A, o4);
        }
        s = quantile5(A);
        if (lanein == 0) scales[b] = s;
    }

    // Per-WG scale min/max partials (invalid threads contribute neutral;
    // 8 lanes with identical s are idempotent under fmin/fmax).
    float mn = valid ? s : FLT_BIG;
    float mx = valid ? s : 0.0f;
#pragma unroll
    for (int off = 32; off > 0; off >>= 1) {
        mn = fminf(mn, __shfl_xor(mn, off, 64));
        mx = fmaxf(mx, __shfl_xor(mx, off, 64));
    }
    __shared__ float smn[4], smx[4];
    const int lane = tid & 63, w = tid >> 6;
    if (lane == 0) { smn[w] = mn; smx[w] = mx; }
    __syncthreads();
    if (tid == 0) {
        float fmn = smn[0], fmx = smx[0];
#pragma unroll
        for (int i = 1; i < 4; ++i) { fmn = fminf(fmn, smn[i]); fmx = fmaxf(fmx, smx[i]); }
        partMin[blockIdx.x] = fmn;
        partMax[blockIdx.x] = fmx;
    }
}

// ---------------- Kernel 2: global smin/smax (v2 verbatim) ----------------
__global__ __launch_bounds__(WG) void k_reduce(const float* __restrict__ partMin,
                                               const float* __restrict__ partMax,
                                               int nparts,
                                               float* __restrict__ hdr) {
    float mn = FLT_BIG, mx = 0.0f;
    for (int i = threadIdx.x; i < nparts; i += WG) {
        mn = fminf(mn, partMin[i]);
        mx = fmaxf(mx, partMax[i]);
    }
#pragma unroll
    for (int off = 32; off > 0; off >>= 1) {
        mn = fminf(mn, __shfl_xor(mn, off, 64));
        mx = fmaxf(mx, __shfl_xor(mx, off, 64));
    }
    __shared__ float smn[4], smx[4];
    int lane = threadIdx.x & 63, w = threadIdx.x >> 6;
    if (lane == 0) { smn[w] = mn; smx[w] = mx; }
    __syncthreads();
    if (threadIdx.x == 0) {
        float fmn = smn[0], fmx = smx[0];
#pragma unroll
        for (int i = 1; i < 4; ++i) { fmn = fminf(fmn, smn[i]); fmx = fmaxf(fmx, smx[i]); }
        hdr[0] = fmn; hdr[1] = fmx;
    }
}

// ---------------- Kernel 3: quantize (v2 verbatim) ----------------
__global__ __launch_bounds__(WG) void k_quant(const float* __restrict__ x,
                                              const float* __restrict__ scales,
                                              const float* __restrict__ hdr,
                                              int n,
                                              float* __restrict__ out) {
    const int t = blockIdx.x * WG + threadIdx.x;
    const int i = t * 4;
    if (i >= n) return;

    const float smin = hdr[0], smax = hdr[1];
    const int b = i >> 6;               // 4-aligned group never crosses a block
    const float s = scales[b];

    // Double-quantization of the scale (exact path).
    float ds;
    if (smax > smin) {
        const float ss = __fdiv_rn(__fsub_rn(smax, smin), 255.0f);
        float q = rintf(__fdiv_rn(__fsub_rn(s, smin), ss));   // round half-even
        q = fminf(fmaxf(q, 0.0f), 255.0f);                    // clip AFTER round
        ds = __fmul_rn(q, ss);
    } else {
        ds = 0.0f;   // q=0, scale_scale=1 -> deq 0
    }

    if (i + 3 < n) {
        const float4 xv = *reinterpret_cast<const float4*>(x + i);
        float4 ov;
        ov.x = __fmul_rn(qlevel(__fdiv_rn(xv.x, s)), ds);
        ov.y = __fmul_rn(qlevel(__fdiv_rn(xv.y, s)), ds);
        ov.z = __fmul_rn(qlevel(__fdiv_rn(xv.z, s)), ds);
        ov.w = __fmul_rn(qlevel(__fdiv_rn(xv.w, s)), ds);
        *reinterpret_cast<float4*>(out + i) = ov;
    } else {
        for (int j = 0; j < 4 && i + j < n; ++j)
            out[i + j] = __fmul_rn(qlevel(__fdiv_rn(x[i + j], s)), ds);
    }
}

extern "C" void kernel_launch(void* const* d_in, const int* in_sizes, int n_in,
                              void* d_out, int out_size, void* d_ws, size_t ws_size,
                              hipStream_t stream) {
    const float* x = (const float*)d_in[0];
    float* out = (float*)d_out;
    const int n = in_sizes[0];
    const int nblocks = (n + BLK - 1) / BLK;          // 262144 for n=16.7M
    const int nwgA = (nblocks + (WG / 8) - 1) / (WG / 8);   // 32 blocks per WG -> 8192

    float* ws = (float*)d_ws;
    float* scales  = ws;                 // nblocks floats
    float* partMin = ws + nblocks;       // nwgA floats
    float* partMax = partMin + nwgA;     // nwgA floats
    float* hdr     = partMax + nwgA;     // 2 floats (smin, smax)

    k_scales<<<nwgA, WG, 0, stream>>>(x, n, nblocks, scales, partMin, partMax);
    k_reduce<<<1, WG, 0, stream>>>(partMin, partMax, nwgA, hdr);
    k_quant<<<((n + 3) / 4 + WG - 1) / WG, WG, 0, stream>>>(x, scales, hdr, n, out);
}